// Round 8
// baseline (1013.860 us; speedup 1.0000x reference)
//
#include <hip/hip_runtime.h>
#include <hip/hip_fp16.h>
#include <cstdint>

#define NCH 128
#define NGRAPHS 64
#define OUTC 10
#define POOL_CHUNK 256
#define NR 16      // dst ranges
#define BXS 32     // edge-slice blocks per range
#define RBMAX 6272 // max bins per range (N<=NR*RBMAX)

typedef __attribute__((ext_vector_type(8))) short s8v;
typedef __attribute__((ext_vector_type(8))) _Float16 h8v;
typedef __attribute__((ext_vector_type(4))) float f4v;

// ---------------- preprocessing: atomic-free counting sort by dst ----------------

// K1: partial histograms of src and dst per (edge-slice x, node-range y), LDS-binned.
__global__ __launch_bounds__(256) void pbin_kernel(const int* __restrict__ ei,
                                                   int* __restrict__ pbinsD,
                                                   int* __restrict__ pbinsS,
                                                   int E, int N, int RB) {
  __shared__ int binD[RBMAX];
  __shared__ int binS[RBMAX];
  int t = threadIdx.x;
  int x = blockIdx.x, y = blockIdx.y;
  for (int b = t; b < RB; b += 256) { binD[b] = 0; binS[b] = 0; }
  __syncthreads();
  int lo = y * RB;
  int hi = min(lo + RB, N);
  int chunk = (E + BXS - 1) / BXS;
  int i0 = x * chunk, i1 = min(i0 + chunk, E);
  for (int i = i0 + t; i < i1; i += 256) {
    int d = ei[E + i];
    if (d >= lo && d < hi) atomicAdd(&binD[d - lo], 1);
    int s = ei[i];
    if (s >= lo && s < hi) atomicAdd(&binS[s - lo], 1);
  }
  __syncthreads();
  size_t base = (size_t)(y * BXS + x) * RB;
  for (int b = t; b < RB; b += 256) {
    pbinsD[base + b] = binD[b];
    pbinsS[base + b] = binS[b];
  }
}

// K2: degree = sum_x src-partials; dis = rsqrt(deg)
__global__ __launch_bounds__(256) void sc_dis_kernel(const int* __restrict__ pbinsS,
                                                     float* __restrict__ dis,
                                                     int N, int RB) {
  int n = blockIdx.x * 256 + threadIdx.x;
  if (n >= N) return;
  int y = n / RB, b = n - y * RB;
  int s = 0;
#pragma unroll
  for (int x = 0; x < BXS; ++x) s += pbinsS[(size_t)(y * BXS + x) * RB + b];
  dis[n] = s > 0 ? rsqrtf((float)s) : 0.0f;
}

// K3: per range y, exclusive scan over (d major, x minor) of dst-partials.
// sbase[y][x][d] = (# in-range edges with dst' < d) + (# edges with dst==d in slices x' < x)
__global__ __launch_bounds__(256) void range_scan_kernel(const int* __restrict__ pbinsD,
                                                         int* __restrict__ sbase,
                                                         int* __restrict__ rtot, int RB) {
  __shared__ int wsum[4];
  __shared__ int carry_s;
  int t = threadIdx.x;
  int y = blockIdx.x;
  if (t == 0) carry_s = 0;
  __syncthreads();
  int nch = (RB + 255) / 256;
  for (int c = 0; c < nch; ++c) {
    int d = c * 256 + t;
    int v[BXS];
    int tv = 0;
#pragma unroll
    for (int x = 0; x < BXS; ++x) {
      v[x] = (d < RB) ? pbinsD[(size_t)(y * BXS + x) * RB + d] : 0;
      tv += v[x];
    }
    int lane = t & 63, w = t >> 6;
    int ps = tv;
    for (int dd = 1; dd < 64; dd <<= 1) {
      int o = __shfl_up(ps, dd);
      if (lane >= dd) ps += o;
    }
    if (lane == 63) wsum[w] = ps;
    __syncthreads();
    int woff = 0;
    for (int i = 0; i < w; ++i) woff += wsum[i];
    int ex = carry_s + woff + ps - tv;  // exclusive prefix within range
    if (d < RB) {
      int run = ex;
#pragma unroll
      for (int x = 0; x < BXS; ++x) {
        sbase[(size_t)(y * BXS + x) * RB + d] = run;
        run += v[x];
      }
    }
    __syncthreads();
    if (t == 0) carry_s += wsum[0] + wsum[1] + wsum[2] + wsum[3];
    __syncthreads();
  }
  if (t == 0) rtot[y] = carry_s;
}

// K3b: scan of 16 range totals
__global__ void base_scan_kernel(const int* __restrict__ rtot, int* __restrict__ base) {
  if (threadIdx.x == 0) {
    int acc = 0;
    for (int y = 0; y < NR; ++y) { base[y] = acc; acc += rtot[y]; }
  }
}

// K4: rp[d] = base[range(d)] + sbase[y][0][d]; rp[N] = E
__global__ __launch_bounds__(256) void rp_kernel(const int* __restrict__ sbase,
                                                 const int* __restrict__ base,
                                                 int* __restrict__ rp, int N, int RB, int E) {
  int n = blockIdx.x * 256 + threadIdx.x;
  if (n < N) {
    int y = n / RB, b = n - y * RB;
    rp[n] = base[y] + sbase[(size_t)(y * BXS) * RB + b];
  } else if (n == N) {
    rp[N] = E;
  }
}

// K5: place edges via LDS counters (no global atomics); writes land in range-local windows
__global__ __launch_bounds__(256) void scatter_sorted_kernel(const int* __restrict__ ei,
                                                             const float* __restrict__ dis,
                                                             const int* __restrict__ sbase,
                                                             const int* __restrict__ base,
                                                             int2* __restrict__ sedge,
                                                             int E, int N, int RB) {
  __shared__ int sb[RBMAX];
  int t = threadIdx.x;
  int x = blockIdx.x, y = blockIdx.y;
  size_t pb = (size_t)(y * BXS + x) * RB;
  for (int b = t; b < RB; b += 256) sb[b] = sbase[pb + b];
  __syncthreads();
  int lo = y * RB;
  int hi = min(lo + RB, N);
  int gbase = base[y];
  int chunk = (E + BXS - 1) / BXS;
  int i0 = x * chunk, i1 = min(i0 + chunk, E);
  for (int i = i0 + t; i < i1; i += 256) {
    int d = ei[E + i];
    if (d < lo || d >= hi) continue;
    int pos = gbase + atomicAdd(&sb[d - lo], 1);
    int s = ei[i];
    sedge[pos] = make_int2(s, __float_as_int(-dis[s] * dis[d]));
  }
}

__global__ __launch_bounds__(256) void f2h_kernel(const float* __restrict__ in,
                                                  __half* __restrict__ out, int n) {
  int i = (blockIdx.x * 256 + threadIdx.x) * 4;
  if (i + 3 < n) {
    float4 v = *(const float4*)&in[i];
    __half2 a = __float22half2_rn(make_float2(v.x, v.y));
    __half2 b = __float22half2_rn(make_float2(v.z, v.w));
    *(__half2*)&out[i] = a;
    *(__half2*)&out[i + 2] = b;
  } else {
    for (; i < n; ++i) out[i] = __float2half(in[i]);
  }
}

// --- weight prep: transpose + fp16 hi/lo(x2^11) split into MFMA-fragment-linear layout ---
__global__ __launch_bounds__(256) void prep_w_kernel(const float* __restrict__ W0,
                                                     const float* __restrict__ W1,
                                                     const float* __restrict__ W2,
                                                     __half* __restrict__ WFhi,
                                                     __half* __restrict__ WFlo) {
  int idx = blockIdx.x * 256 + threadIdx.x;
  const int TOT = 3 * 3 * 128 * 128;
  if (idx >= TOT) return;
  int j = idx & 7;
  int lane = (idx >> 3) & 63;
  int ct = (idx >> 9) & 7;
  int kwin = (idx >> 12) & 3;
  int p = (idx >> 14) % 3;
  int L = idx / (3 * 16384);
  int k = kwin * 32 + (lane >> 4) * 8 + j;
  int col = ct * 16 + (lane & 15);
  const float* W = (L == 0) ? W0 : ((L == 1) ? W1 : W2);
  float v = W[(p * 128 + k) * 128 + col];
  __half hi = __float2half_rn(v);
  float resid = v - __half2float(hi);
  __half lo = __float2half_rn(resid * 2048.0f);
  WFhi[idx] = hi;
  WFlo[idx] = lo;
}

// ---------------- propagate (fp16 operand): out[i] = sum_e norm_e * h[src_e] ----------------
__global__ __launch_bounds__(256) void prop_kernel(const __half* __restrict__ h,
                                                   __half* __restrict__ out,
                                                   const int* __restrict__ rp,
                                                   const int2* __restrict__ sedge, int N) {
  int node = blockIdx.x * 4 + (threadIdx.x >> 6);
  if (node >= N) return;
  int lane = threadIdx.x & 63;
  int half = lane >> 5;
  int c = (lane & 31) * 4;
  int e0 = rp[node], e1 = rp[node + 1];
  float a0 = 0.f, a1 = 0.f, a2 = 0.f, a3 = 0.f;
  int e = e0;
  for (; e + 8 <= e1; e += 8) {
#pragma unroll
    for (int u = 0; u < 4; ++u) {
      int2 Ed = sedge[e + 2 * u + half];
      float w = __int_as_float(Ed.y);
      uint2 raw = *(const uint2*)&h[(size_t)Ed.x * NCH + c];
      __half2 p = *(__half2*)&raw.x, q = *(__half2*)&raw.y;
      float2 f0 = __half22float2(p), f1 = __half22float2(q);
      a0 += w * f0.x; a1 += w * f0.y; a2 += w * f1.x; a3 += w * f1.y;
    }
  }
  if (e < e1) {
#pragma unroll
    for (int u = 0; u < 4; ++u) {
      int idx = e + 2 * u + half;
      if (idx < e1) {
        int2 Ed = sedge[idx];
        float w = __int_as_float(Ed.y);
        uint2 raw = *(const uint2*)&h[(size_t)Ed.x * NCH + c];
        __half2 p = *(__half2*)&raw.x, q = *(__half2*)&raw.y;
        float2 f0 = __half22float2(p), f1 = __half22float2(q);
        a0 += w * f0.x; a1 += w * f0.y; a2 += w * f1.x; a3 += w * f1.y;
      }
    }
  }
  a0 += __shfl_xor(a0, 32); a1 += __shfl_xor(a1, 32);
  a2 += __shfl_xor(a2, 32); a3 += __shfl_xor(a3, 32);
  if (half == 0) {
    __half2 r0 = __float22half2_rn(make_float2(a0, a1));
    __half2 r1 = __float22half2_rn(make_float2(a2, a3));
    uint2 st;
    st.x = *(unsigned*)&r0;
    st.y = *(unsigned*)&r1;
    *(uint2*)&out[(size_t)node * NCH + c] = st;
  }
}

// ------- fused Cheb GEMM via native f16 MFMA -------
__global__ __launch_bounds__(256) void gemm_cheb_mfma(
    const __half* h, const __half* p1, const __half* p2,
    const __half* __restrict__ WFhi, const __half* __restrict__ WFlo,
    const float* __restrict__ bias, __half* out, int N, int relu) {
  __shared__ __align__(16) __half As[1024 * 8];
  int t = threadIdx.x;
  int w = t >> 6, lane = t & 63;
  int rowBase = blockIdx.x * 128;

  f4v accH[2][8], accL[2][8];
#pragma unroll
  for (int rt = 0; rt < 2; ++rt)
#pragma unroll
    for (int ct = 0; ct < 8; ++ct) { accH[rt][ct] = (f4v)0.f; accL[rt][ct] = (f4v)0.f; }

  int pre_row[4], pre_kc[4];
#pragma unroll
  for (int p = 0; p < 4; ++p) {
    int g = p * 256 + t;
    int slot = g >> 6, lidx = g & 63;
    pre_row[p] = (slot >> 2) * 32 + ((slot >> 1) & 1) * 16 + (lidx & 15);
    pre_kc[p] = (slot & 1) * 4 + (lidx >> 4);
  }

  for (int s = 0; s < 6; ++s) {
    int phase = s >> 1;
    int k0 = (s & 1) * 64;
    if (s) __syncthreads();
#pragma unroll
    for (int p = 0; p < 4; ++p) {
      int gRow = rowBase + pre_row[p];
      int gR = min(gRow, N - 1);
      int gk = k0 + pre_kc[p] * 8;
      s8v chunk;
      if (phase == 0) {
        chunk = *(const s8v*)&h[(size_t)gR * NCH + gk];
      } else if (phase == 1) {
        chunk = *(const s8v*)&p1[(size_t)gR * NCH + gk];
      } else {
        union { s8v v; __half2 h2[4]; } a, b, r;
        a.v = *(const s8v*)&p2[(size_t)gR * NCH + gk];
        b.v = *(const s8v*)&h[(size_t)gR * NCH + gk];
        const __half2 two = __floats2half2_rn(2.f, 2.f);
#pragma unroll
        for (int j = 0; j < 4; ++j) r.h2[j] = __hsub2(__hmul2(two, a.h2[j]), b.h2[j]);
        chunk = r.v;
      }
      *(s8v*)&As[(size_t)(p * 256 + t) * 8] = chunk;
    }
    __syncthreads();
    h8v a[2][2];
#pragma unroll
    for (int rt = 0; rt < 2; ++rt)
#pragma unroll
      for (int kw = 0; kw < 2; ++kw)
        a[rt][kw] = *(const h8v*)&As[(size_t)((((w * 2 + rt) * 2 + kw) * 64) + lane) * 8];
#pragma unroll
    for (int ct = 0; ct < 8; ++ct) {
#pragma unroll
      for (int kw = 0; kw < 2; ++kw) {
        int kwin = (s & 1) * 2 + kw;
        int boff = (phase * 4 + kwin) * 4096 + ct * 512 + lane * 8;
        h8v bh = *(const h8v*)&WFhi[boff];
        h8v bl = *(const h8v*)&WFlo[boff];
#pragma unroll
        for (int rt = 0; rt < 2; ++rt) {
          accH[rt][ct] = __builtin_amdgcn_mfma_f32_16x16x32_f16(a[rt][kw], bh, accH[rt][ct], 0, 0, 0);
          accL[rt][ct] = __builtin_amdgcn_mfma_f32_16x16x32_f16(a[rt][kw], bl, accL[rt][ct], 0, 0, 0);
        }
      }
    }
  }
  int crow = (lane >> 4) * 4;
  int ccol = lane & 15;
  const float inv2048 = 1.0f / 2048.0f;
#pragma unroll
  for (int rt = 0; rt < 2; ++rt) {
    int gRow0 = rowBase + (w * 2 + rt) * 16 + crow;
#pragma unroll
    for (int reg = 0; reg < 4; ++reg) {
      int gRow = gRow0 + reg;
      if (gRow >= N) continue;
#pragma unroll
      for (int ct = 0; ct < 8; ++ct) {
        int col = ct * 16 + ccol;
        float vv = accH[rt][ct][reg] + accL[rt][ct][reg] * inv2048 + bias[col];
        if (relu) vv = fmaxf(vv, 0.f);
        out[(size_t)gRow * NCH + col] = __float2half(vv);
      }
    }
  }
}

// ---------------- pooling + final linear ----------------

__global__ __launch_bounds__(128) void pool_kernel(const __half* __restrict__ h,
                                                   const int* __restrict__ batch,
                                                   float* __restrict__ sums,
                                                   float* __restrict__ gcnt, int N) {
  int start = blockIdx.x * POOL_CHUNK;
  if (start >= N) return;
  int end = min(start + POOL_CHUNK, N);
  int c = threadIdx.x;
  float acc = 0.f;
  int cnt = 0;
  int cur = batch[start];
  for (int i = start; i < end; ++i) {
    int g = batch[i];
    if (g != cur) {
      atomicAdd(&sums[cur * NCH + c], acc);
      if (c == 0) atomicAdd(&gcnt[cur], (float)cnt);
      acc = 0.f; cnt = 0; cur = g;
    }
    acc += __half2float(h[(size_t)i * NCH + c]);
    ++cnt;
  }
  atomicAdd(&sums[cur * NCH + c], acc);
  if (c == 0) atomicAdd(&gcnt[cur], (float)cnt);
}

__global__ void final_kernel(const float* __restrict__ sums, const float* __restrict__ gcnt,
                             const float* __restrict__ lw, const float* __restrict__ lb,
                             float* __restrict__ out) {
  int g = blockIdx.x;
  int o = threadIdx.x;
  if (o >= OUTC) return;
  float inv = 1.0f / fmaxf(gcnt[g], 1.0f);
  float acc = lb[o];
  for (int ch = 0; ch < NCH; ++ch) acc += sums[g * NCH + ch] * inv * lw[ch * OUTC + o];
  out[g * OUTC + o] = acc;
}

// ---------------- launch ----------------

extern "C" void kernel_launch(void* const* d_in, const int* in_sizes, int n_in,
                              void* d_out, int out_size, void* d_ws, size_t ws_size,
                              hipStream_t stream) {
  const float* x  = (const float*)d_in[0];
  const int* ei   = (const int*)d_in[1];
  const int* batch= (const int*)d_in[2];
  const float* W0 = (const float*)d_in[3];
  const float* b0 = (const float*)d_in[4];
  const float* W1 = (const float*)d_in[5];
  const float* b1 = (const float*)d_in[6];
  const float* W2 = (const float*)d_in[7];
  const float* b2 = (const float*)d_in[8];
  const float* lw = (const float*)d_in[9];
  const float* lb = (const float*)d_in[10];
  float* out = (float*)d_out;
  int N = in_sizes[0] / NCH;
  int E = in_sizes[1] / 2;
  int RB = (N + NR - 1) / NR;  // bins per range (<= RBMAX)

  char* ws = (char*)d_ws;
  size_t off = 0;
  auto take = [&](size_t bytes) -> char* {
    char* p = ws + off;
    off += (bytes + 511) & ~(size_t)511;
    return p;
  };
  int* pbinsD  = (int*)take((size_t)NR * BXS * RB * 4);
  int* pbinsS  = (int*)take((size_t)NR * BXS * RB * 4);
  int* sbase   = (int*)take((size_t)NR * BXS * RB * 4);
  int* rtot    = (int*)take(NR * 4);
  int* gbase   = (int*)take(NR * 4);
  float* dis   = (float*)take((size_t)N * 4);
  int* rp      = (int*)take((size_t)(N + 1) * 4);
  int2* sedge  = (int2*)take((size_t)E * 8);
  __half* x16  = (__half*)take((size_t)N * NCH * 2);
  __half* H16  = (__half*)take((size_t)N * NCH * 2);
  __half* P1h  = (__half*)take((size_t)N * NCH * 2);
  __half* P2h  = (__half*)take((size_t)N * NCH * 2);
  __half* WFhi = (__half*)take((size_t)3 * 3 * 128 * 128 * 2);
  __half* WFlo = (__half*)take((size_t)3 * 3 * 128 * 128 * 2);
  float* sums  = (float*)take((size_t)NGRAPHS * NCH * 4);
  float* gcnt  = (float*)take((size_t)NGRAPHS * 4);

  hipMemsetAsync(sums, 0, (size_t)NGRAPHS * NCH * 4, stream);
  hipMemsetAsync(gcnt, 0, (size_t)NGRAPHS * 4, stream);

  prep_w_kernel<<<(3 * 3 * 128 * 128 + 255) / 256, 256, 0, stream>>>(W0, W1, W2, WFhi, WFlo);
  f2h_kernel<<<(N * NCH / 4 + 255) / 256, 256, 0, stream>>>(x, x16, N * NCH);

  {
    dim3 g(BXS, NR, 1);
    pbin_kernel<<<g, 256, 0, stream>>>(ei, pbinsD, pbinsS, E, N, RB);
  }
  sc_dis_kernel<<<(N + 255) / 256, 256, 0, stream>>>(pbinsS, dis, N, RB);
  range_scan_kernel<<<NR, 256, 0, stream>>>(pbinsD, sbase, rtot, RB);
  base_scan_kernel<<<1, 64, 0, stream>>>(rtot, gbase);
  rp_kernel<<<(N + 1 + 255) / 256, 256, 0, stream>>>(sbase, gbase, rp, N, RB, E);
  {
    dim3 g(BXS, NR, 1);
    scatter_sorted_kernel<<<g, 256, 0, stream>>>(ei, dis, sbase, gbase, sedge, E, N, RB);
  }

  int pgrid = (N + 3) / 4;
  int ggrid = (N + 127) / 128;
  const int WL = 3 * 4 * 8 * 512;  // halfs per layer in WF layout

  // layer 0
  prop_kernel<<<pgrid, 256, 0, stream>>>(x16, P1h, rp, sedge, N);
  prop_kernel<<<pgrid, 256, 0, stream>>>(P1h, P2h, rp, sedge, N);
  gemm_cheb_mfma<<<ggrid, 256, 0, stream>>>(x16, P1h, P2h, WFhi + 0 * WL, WFlo + 0 * WL, b0, H16, N, 1);
  // layer 1 (out aliases h; safe: blocks own disjoint rows, reads precede final barrier)
  prop_kernel<<<pgrid, 256, 0, stream>>>(H16, P1h, rp, sedge, N);
  prop_kernel<<<pgrid, 256, 0, stream>>>(P1h, P2h, rp, sedge, N);
  gemm_cheb_mfma<<<ggrid, 256, 0, stream>>>(H16, P1h, P2h, WFhi + 1 * WL, WFlo + 1 * WL, b1, H16, N, 1);
  // layer 2
  prop_kernel<<<pgrid, 256, 0, stream>>>(H16, P1h, rp, sedge, N);
  prop_kernel<<<pgrid, 256, 0, stream>>>(P1h, P2h, rp, sedge, N);
  gemm_cheb_mfma<<<ggrid, 256, 0, stream>>>(H16, P1h, P2h, WFhi + 2 * WL, WFlo + 2 * WL, b2, H16, N, 0);

  pool_kernel<<<(N + POOL_CHUNK - 1) / POOL_CHUNK, 128, 0, stream>>>(H16, batch, sums, gcnt, N);
  final_kernel<<<NGRAPHS, 16, 0, stream>>>(sums, gcnt, lw, lb, out);
}

// Round 9
// 897.719 us; speedup vs baseline: 1.1294x; 1.1294x over previous
//
#include <hip/hip_runtime.h>
#include <hip/hip_fp16.h>
#include <cstdint>

#define NCH 128
#define NGRAPHS 64
#define OUTC 10
#define POOL_CHUNK 256
#define NR 16      // dst/src ranges
#define BXS 32     // sub-blocks per range for bin/place
#define NBLK 512   // blocks for part/partition passes
#define RBMAX 6272 // max bins per range (N <= NR*RBMAX)

typedef __attribute__((ext_vector_type(8))) short s8v;
typedef __attribute__((ext_vector_type(8))) _Float16 h8v;
typedef __attribute__((ext_vector_type(4))) float f4v;

// ---------------- preprocessing: partition + counting sort, zero global atomics ----------------

// P1: per-block counts of dst-range and src-range
__global__ __launch_bounds__(256) void part_count_kernel(const int* __restrict__ ei,
                                                         int* __restrict__ pc,
                                                         int* __restrict__ pcS,
                                                         int E, int RB) {
  __shared__ int cd[NR], cs[NR];
  int t = threadIdx.x, b = blockIdx.x;
  if (t < NR) { cd[t] = 0; cs[t] = 0; }
  __syncthreads();
  int chunk = (E + NBLK - 1) / NBLK;
  int i0 = b * chunk, i1 = min(i0 + chunk, E);
  for (int i = i0 + t; i < i1; i += 256) {
    atomicAdd(&cd[(unsigned)ei[E + i] / (unsigned)RB], 1);
    atomicAdd(&cs[(unsigned)ei[i] / (unsigned)RB], 1);
  }
  __syncthreads();
  if (t < NR) { pc[b * NR + t] = cd[t]; pcS[b * NR + t] = cs[t]; }
}

// P2: scans -> per-(block,range) cursors + segment bases (gbase for dst, sgbase for src)
__global__ void offs_kernel(const int* __restrict__ pc, const int* __restrict__ pcS,
                            int* __restrict__ pairOff, int* __restrict__ srcOff,
                            int* __restrict__ gbase, int* __restrict__ sgbase, int E) {
  __shared__ int tot[NR], totS[NR];
  int t = threadIdx.x;
  if (t < NR) {
    int a = 0, as = 0;
    for (int b = 0; b < NBLK; ++b) { a += pc[b * NR + t]; as += pcS[b * NR + t]; }
    tot[t] = a; totS[t] = as;
  }
  __syncthreads();
  if (t == 0) {
    int acc = 0, accS = 0;
    for (int r = 0; r < NR; ++r) {
      gbase[r] = acc; acc += tot[r];
      sgbase[r] = accS; accS += totS[r];
    }
    gbase[NR] = E; sgbase[NR] = E;
  }
  __syncthreads();
  if (t < NR) {
    int acc = gbase[t], accS = sgbase[t];
    for (int b = 0; b < NBLK; ++b) {
      pairOff[b * NR + t] = acc; acc += pc[b * NR + t];
      srcOff[b * NR + t] = accS; accS += pcS[b * NR + t];
    }
  }
}

// P3: partition edges by dst-range (dsts,srcs) and src values by src-range (srcpart)
__global__ __launch_bounds__(256) void partition_kernel(const int* __restrict__ ei,
                                                        const int* __restrict__ pairOff,
                                                        const int* __restrict__ srcOff,
                                                        int* __restrict__ dsts,
                                                        int* __restrict__ srcs,
                                                        int* __restrict__ srcpart,
                                                        int E, int RB) {
  __shared__ int baseD[NR], baseS[NR], ctrD[NR], ctrS[NR];
  int t = threadIdx.x, b = blockIdx.x;
  if (t < NR) {
    baseD[t] = pairOff[b * NR + t]; ctrD[t] = 0;
    baseS[t] = srcOff[b * NR + t]; ctrS[t] = 0;
  }
  __syncthreads();
  int chunk = (E + NBLK - 1) / NBLK;
  int i0 = b * chunk, i1 = min(i0 + chunk, E);
  for (int i = i0 + t; i < i1; i += 256) {
    int d = ei[E + i], s = ei[i];
    int r = (unsigned)d / (unsigned)RB;
    int k = atomicAdd(&ctrD[r], 1);
    int pos = baseD[r] + k;
    dsts[pos] = d; srcs[pos] = s;
    int rs = (unsigned)s / (unsigned)RB;
    int k2 = atomicAdd(&ctrS[rs], 1);
    srcpart[baseS[rs] + k2] = s;
  }
}

// P4a: exact-dst partial bins per (slice x, range y) over the partitioned dsts
__global__ __launch_bounds__(256) void binD_kernel(const int* __restrict__ dsts,
                                                   const int* __restrict__ gbase,
                                                   int* __restrict__ pbinsD, int RB) {
  __shared__ int bin[RBMAX];
  int t = threadIdx.x, x = blockIdx.x, y = blockIdx.y;
  for (int b = t; b < RB; b += 256) bin[b] = 0;
  __syncthreads();
  int segS = gbase[y], segE = gbase[y + 1];
  int chunk = (segE - segS + BXS - 1) / BXS;
  int i0 = segS + x * chunk, i1 = min(i0 + chunk, segE);
  int lo = y * RB;
  for (int i = i0 + t; i < i1; i += 256) atomicAdd(&bin[dsts[i] - lo], 1);
  __syncthreads();
  size_t base = (size_t)(y * BXS + x) * RB;
  for (int b = t; b < RB; b += 256) pbinsD[base + b] = bin[b];
}

// P4b: exact-src partial bins over srcpart (for degree)
__global__ __launch_bounds__(256) void binS_kernel(const int* __restrict__ srcpart,
                                                   const int* __restrict__ sgbase,
                                                   int* __restrict__ pbinsS, int RB) {
  __shared__ int bin[RBMAX];
  int t = threadIdx.x, x = blockIdx.x, y = blockIdx.y;
  for (int b = t; b < RB; b += 256) bin[b] = 0;
  __syncthreads();
  int segS = sgbase[y], segE = sgbase[y + 1];
  int chunk = (segE - segS + BXS - 1) / BXS;
  int i0 = segS + x * chunk, i1 = min(i0 + chunk, segE);
  int lo = y * RB;
  for (int i = i0 + t; i < i1; i += 256) atomicAdd(&bin[srcpart[i] - lo], 1);
  __syncthreads();
  size_t base = (size_t)(y * BXS + x) * RB;
  for (int b = t; b < RB; b += 256) pbinsS[base + b] = bin[b];
}

// degree = sum_x src-partials; dis = rsqrt(deg)
__global__ __launch_bounds__(256) void sc_dis_kernel(const int* __restrict__ pbinsS,
                                                     float* __restrict__ dis,
                                                     int N, int RB) {
  int n = blockIdx.x * 256 + threadIdx.x;
  if (n >= N) return;
  int y = n / RB, b = n - y * RB;
  int s = 0;
#pragma unroll
  for (int x = 0; x < BXS; ++x) s += pbinsS[(size_t)(y * BXS + x) * RB + b];
  dis[n] = s > 0 ? rsqrtf((float)s) : 0.0f;
}

// per range y: exclusive scan over (d major, x minor) of dst-partials -> sbase
__global__ __launch_bounds__(256) void range_scan_kernel(const int* __restrict__ pbinsD,
                                                         int* __restrict__ sbase, int RB) {
  __shared__ int wsum[4];
  __shared__ int carry_s;
  int t = threadIdx.x;
  int y = blockIdx.x;
  if (t == 0) carry_s = 0;
  __syncthreads();
  int nch = (RB + 255) / 256;
  for (int c = 0; c < nch; ++c) {
    int d = c * 256 + t;
    int v[BXS];
    int tv = 0;
#pragma unroll
    for (int x = 0; x < BXS; ++x) {
      v[x] = (d < RB) ? pbinsD[(size_t)(y * BXS + x) * RB + d] : 0;
      tv += v[x];
    }
    int lane = t & 63, w = t >> 6;
    int ps = tv;
    for (int dd = 1; dd < 64; dd <<= 1) {
      int o = __shfl_up(ps, dd);
      if (lane >= dd) ps += o;
    }
    if (lane == 63) wsum[w] = ps;
    __syncthreads();
    int woff = 0;
    for (int i = 0; i < w; ++i) woff += wsum[i];
    int ex = carry_s + woff + ps - tv;
    if (d < RB) {
      int run = ex;
#pragma unroll
      for (int x = 0; x < BXS; ++x) {
        sbase[(size_t)(y * BXS + x) * RB + d] = run;
        run += v[x];
      }
    }
    __syncthreads();
    if (t == 0) carry_s += wsum[0] + wsum[1] + wsum[2] + wsum[3];
    __syncthreads();
  }
}

// rp[d] = gbase[range] + sbase[y][0][d]; rp[N] = E
__global__ __launch_bounds__(256) void rp_kernel(const int* __restrict__ sbase,
                                                 const int* __restrict__ gbase,
                                                 int* __restrict__ rp, int N, int RB, int E) {
  int n = blockIdx.x * 256 + threadIdx.x;
  if (n < N) {
    int y = n / RB, b = n - y * RB;
    rp[n] = gbase[y] + sbase[(size_t)(y * BXS) * RB + b];
  } else if (n == N) {
    rp[N] = E;
  }
}

// P6: place partitioned pairs via LDS cursors; writes land in range-local windows
__global__ __launch_bounds__(256) void place_kernel(const int* __restrict__ dsts,
                                                    const int* __restrict__ srcs,
                                                    const float* __restrict__ dis,
                                                    const int* __restrict__ sbase,
                                                    const int* __restrict__ gbase,
                                                    int2* __restrict__ sedge, int RB) {
  __shared__ int sb[RBMAX];
  int t = threadIdx.x, x = blockIdx.x, y = blockIdx.y;
  size_t pb = (size_t)(y * BXS + x) * RB;
  for (int b = t; b < RB; b += 256) sb[b] = sbase[pb + b];
  __syncthreads();
  int segS = gbase[y], segE = gbase[y + 1];
  int chunk = (segE - segS + BXS - 1) / BXS;
  int i0 = segS + x * chunk, i1 = min(i0 + chunk, segE);
  int lo = y * RB;
  int gb = gbase[y];
  for (int i = i0 + t; i < i1; i += 256) {
    int d = dsts[i], s = srcs[i];
    int pos = gb + atomicAdd(&sb[d - lo], 1);
    sedge[pos] = make_int2(s, __float_as_int(-dis[s] * dis[d]));
  }
}

__global__ __launch_bounds__(256) void f2h_kernel(const float* __restrict__ in,
                                                  __half* __restrict__ out, int n) {
  int i = (blockIdx.x * 256 + threadIdx.x) * 4;
  if (i + 3 < n) {
    float4 v = *(const float4*)&in[i];
    __half2 a = __float22half2_rn(make_float2(v.x, v.y));
    __half2 b = __float22half2_rn(make_float2(v.z, v.w));
    *(__half2*)&out[i] = a;
    *(__half2*)&out[i + 2] = b;
  } else {
    for (; i < n; ++i) out[i] = __float2half(in[i]);
  }
}

// --- weight prep: transpose + fp16 hi/lo(x2^11) split into MFMA-fragment-linear layout ---
__global__ __launch_bounds__(256) void prep_w_kernel(const float* __restrict__ W0,
                                                     const float* __restrict__ W1,
                                                     const float* __restrict__ W2,
                                                     __half* __restrict__ WFhi,
                                                     __half* __restrict__ WFlo) {
  int idx = blockIdx.x * 256 + threadIdx.x;
  const int TOT = 3 * 3 * 128 * 128;
  if (idx >= TOT) return;
  int j = idx & 7;
  int lane = (idx >> 3) & 63;
  int ct = (idx >> 9) & 7;
  int kwin = (idx >> 12) & 3;
  int p = (idx >> 14) % 3;
  int L = idx / (3 * 16384);
  int k = kwin * 32 + (lane >> 4) * 8 + j;
  int col = ct * 16 + (lane & 15);
  const float* W = (L == 0) ? W0 : ((L == 1) ? W1 : W2);
  float v = W[(p * 128 + k) * 128 + col];
  __half hi = __float2half_rn(v);
  float resid = v - __half2float(hi);
  __half lo = __float2half_rn(resid * 2048.0f);
  WFhi[idx] = hi;
  WFlo[idx] = lo;
}

// ---------------- propagate (fp16 operand): out[i] = sum_e norm_e * h[src_e] ----------------
__global__ __launch_bounds__(256) void prop_kernel(const __half* __restrict__ h,
                                                   __half* __restrict__ out,
                                                   const int* __restrict__ rp,
                                                   const int2* __restrict__ sedge, int N) {
  int node = blockIdx.x * 4 + (threadIdx.x >> 6);
  if (node >= N) return;
  int lane = threadIdx.x & 63;
  int half = lane >> 5;
  int c = (lane & 31) * 4;
  int e0 = rp[node], e1 = rp[node + 1];
  float a0 = 0.f, a1 = 0.f, a2 = 0.f, a3 = 0.f;
  int e = e0;
  for (; e + 8 <= e1; e += 8) {
#pragma unroll
    for (int u = 0; u < 4; ++u) {
      int2 Ed = sedge[e + 2 * u + half];
      float w = __int_as_float(Ed.y);
      uint2 raw = *(const uint2*)&h[(size_t)Ed.x * NCH + c];
      __half2 p = *(__half2*)&raw.x, q = *(__half2*)&raw.y;
      float2 f0 = __half22float2(p), f1 = __half22float2(q);
      a0 += w * f0.x; a1 += w * f0.y; a2 += w * f1.x; a3 += w * f1.y;
    }
  }
  if (e < e1) {
#pragma unroll
    for (int u = 0; u < 4; ++u) {
      int idx = e + 2 * u + half;
      if (idx < e1) {
        int2 Ed = sedge[idx];
        float w = __int_as_float(Ed.y);
        uint2 raw = *(const uint2*)&h[(size_t)Ed.x * NCH + c];
        __half2 p = *(__half2*)&raw.x, q = *(__half2*)&raw.y;
        float2 f0 = __half22float2(p), f1 = __half22float2(q);
        a0 += w * f0.x; a1 += w * f0.y; a2 += w * f1.x; a3 += w * f1.y;
      }
    }
  }
  a0 += __shfl_xor(a0, 32); a1 += __shfl_xor(a1, 32);
  a2 += __shfl_xor(a2, 32); a3 += __shfl_xor(a3, 32);
  if (half == 0) {
    __half2 r0 = __float22half2_rn(make_float2(a0, a1));
    __half2 r1 = __float22half2_rn(make_float2(a2, a3));
    uint2 st;
    st.x = *(unsigned*)&r0;
    st.y = *(unsigned*)&r1;
    *(uint2*)&out[(size_t)node * NCH + c] = st;
  }
}

// ------- fused Cheb GEMM via native f16 MFMA -------
__global__ __launch_bounds__(256) void gemm_cheb_mfma(
    const __half* h, const __half* p1, const __half* p2,
    const __half* __restrict__ WFhi, const __half* __restrict__ WFlo,
    const float* __restrict__ bias, __half* out, int N, int relu) {
  __shared__ __align__(16) __half As[1024 * 8];
  int t = threadIdx.x;
  int w = t >> 6, lane = t & 63;
  int rowBase = blockIdx.x * 128;

  f4v accH[2][8], accL[2][8];
#pragma unroll
  for (int rt = 0; rt < 2; ++rt)
#pragma unroll
    for (int ct = 0; ct < 8; ++ct) { accH[rt][ct] = (f4v)0.f; accL[rt][ct] = (f4v)0.f; }

  int pre_row[4], pre_kc[4];
#pragma unroll
  for (int p = 0; p < 4; ++p) {
    int g = p * 256 + t;
    int slot = g >> 6, lidx = g & 63;
    pre_row[p] = (slot >> 2) * 32 + ((slot >> 1) & 1) * 16 + (lidx & 15);
    pre_kc[p] = (slot & 1) * 4 + (lidx >> 4);
  }

  for (int s = 0; s < 6; ++s) {
    int phase = s >> 1;
    int k0 = (s & 1) * 64;
    if (s) __syncthreads();
#pragma unroll
    for (int p = 0; p < 4; ++p) {
      int gRow = rowBase + pre_row[p];
      int gR = min(gRow, N - 1);
      int gk = k0 + pre_kc[p] * 8;
      s8v chunk;
      if (phase == 0) {
        chunk = *(const s8v*)&h[(size_t)gR * NCH + gk];
      } else if (phase == 1) {
        chunk = *(const s8v*)&p1[(size_t)gR * NCH + gk];
      } else {
        union { s8v v; __half2 h2[4]; } a, b, r;
        a.v = *(const s8v*)&p2[(size_t)gR * NCH + gk];
        b.v = *(const s8v*)&h[(size_t)gR * NCH + gk];
        const __half2 two = __floats2half2_rn(2.f, 2.f);
#pragma unroll
        for (int j = 0; j < 4; ++j) r.h2[j] = __hsub2(__hmul2(two, a.h2[j]), b.h2[j]);
        chunk = r.v;
      }
      *(s8v*)&As[(size_t)(p * 256 + t) * 8] = chunk;
    }
    __syncthreads();
    h8v a[2][2];
#pragma unroll
    for (int rt = 0; rt < 2; ++rt)
#pragma unroll
      for (int kw = 0; kw < 2; ++kw)
        a[rt][kw] = *(const h8v*)&As[(size_t)((((w * 2 + rt) * 2 + kw) * 64) + lane) * 8];
#pragma unroll
    for (int ct = 0; ct < 8; ++ct) {
#pragma unroll
      for (int kw = 0; kw < 2; ++kw) {
        int kwin = (s & 1) * 2 + kw;
        int boff = (phase * 4 + kwin) * 4096 + ct * 512 + lane * 8;
        h8v bh = *(const h8v*)&WFhi[boff];
        h8v bl = *(const h8v*)&WFlo[boff];
#pragma unroll
        for (int rt = 0; rt < 2; ++rt) {
          accH[rt][ct] = __builtin_amdgcn_mfma_f32_16x16x32_f16(a[rt][kw], bh, accH[rt][ct], 0, 0, 0);
          accL[rt][ct] = __builtin_amdgcn_mfma_f32_16x16x32_f16(a[rt][kw], bl, accL[rt][ct], 0, 0, 0);
        }
      }
    }
  }
  int crow = (lane >> 4) * 4;
  int ccol = lane & 15;
  const float inv2048 = 1.0f / 2048.0f;
#pragma unroll
  for (int rt = 0; rt < 2; ++rt) {
    int gRow0 = rowBase + (w * 2 + rt) * 16 + crow;
#pragma unroll
    for (int reg = 0; reg < 4; ++reg) {
      int gRow = gRow0 + reg;
      if (gRow >= N) continue;
#pragma unroll
      for (int ct = 0; ct < 8; ++ct) {
        int col = ct * 16 + ccol;
        float vv = accH[rt][ct][reg] + accL[rt][ct][reg] * inv2048 + bias[col];
        if (relu) vv = fmaxf(vv, 0.f);
        out[(size_t)gRow * NCH + col] = __float2half(vv);
      }
    }
  }
}

// ---------------- pooling + final linear ----------------

__global__ __launch_bounds__(128) void pool_kernel(const __half* __restrict__ h,
                                                   const int* __restrict__ batch,
                                                   float* __restrict__ sums,
                                                   float* __restrict__ gcnt, int N) {
  int start = blockIdx.x * POOL_CHUNK;
  if (start >= N) return;
  int end = min(start + POOL_CHUNK, N);
  int c = threadIdx.x;
  float acc = 0.f;
  int cnt = 0;
  int cur = batch[start];
  for (int i = start; i < end; ++i) {
    int g = batch[i];
    if (g != cur) {
      atomicAdd(&sums[cur * NCH + c], acc);
      if (c == 0) atomicAdd(&gcnt[cur], (float)cnt);
      acc = 0.f; cnt = 0; cur = g;
    }
    acc += __half2float(h[(size_t)i * NCH + c]);
    ++cnt;
  }
  atomicAdd(&sums[cur * NCH + c], acc);
  if (c == 0) atomicAdd(&gcnt[cur], (float)cnt);
}

__global__ void final_kernel(const float* __restrict__ sums, const float* __restrict__ gcnt,
                             const float* __restrict__ lw, const float* __restrict__ lb,
                             float* __restrict__ out) {
  int g = blockIdx.x;
  int o = threadIdx.x;
  if (o >= OUTC) return;
  float inv = 1.0f / fmaxf(gcnt[g], 1.0f);
  float acc = lb[o];
  for (int ch = 0; ch < NCH; ++ch) acc += sums[g * NCH + ch] * inv * lw[ch * OUTC + o];
  out[g * OUTC + o] = acc;
}

// ---------------- launch ----------------

extern "C" void kernel_launch(void* const* d_in, const int* in_sizes, int n_in,
                              void* d_out, int out_size, void* d_ws, size_t ws_size,
                              hipStream_t stream) {
  const float* x  = (const float*)d_in[0];
  const int* ei   = (const int*)d_in[1];
  const int* batch= (const int*)d_in[2];
  const float* W0 = (const float*)d_in[3];
  const float* b0 = (const float*)d_in[4];
  const float* W1 = (const float*)d_in[5];
  const float* b1 = (const float*)d_in[6];
  const float* W2 = (const float*)d_in[7];
  const float* b2 = (const float*)d_in[8];
  const float* lw = (const float*)d_in[9];
  const float* lb = (const float*)d_in[10];
  float* out = (float*)d_out;
  int N = in_sizes[0] / NCH;
  int E = in_sizes[1] / 2;
  int RB = (N + NR - 1) / NR;  // bins per range (<= RBMAX)

  char* ws = (char*)d_ws;
  size_t off = 0;
  auto take = [&](size_t bytes) -> char* {
    char* p = ws + off;
    off += (bytes + 511) & ~(size_t)511;
    return p;
  };
  int* pc      = (int*)take((size_t)NBLK * NR * 4);
  int* pcS     = (int*)take((size_t)NBLK * NR * 4);
  int* pairOff = (int*)take((size_t)NBLK * NR * 4);
  int* srcOff  = (int*)take((size_t)NBLK * NR * 4);
  int* gbase   = (int*)take((NR + 1) * 4);
  int* sgbase  = (int*)take((NR + 1) * 4);
  int* dsts    = (int*)take((size_t)E * 4);
  int* srcs    = (int*)take((size_t)E * 4);
  int* srcpart = (int*)take((size_t)E * 4);
  int* pbinsD  = (int*)take((size_t)NR * BXS * RB * 4);
  int* pbinsS  = (int*)take((size_t)NR * BXS * RB * 4);
  int* sbase   = (int*)take((size_t)NR * BXS * RB * 4);
  float* dis   = (float*)take((size_t)N * 4);
  int* rp      = (int*)take((size_t)(N + 1) * 4);
  int2* sedge  = (int2*)take((size_t)E * 8);
  __half* x16  = (__half*)take((size_t)N * NCH * 2);
  __half* H16  = (__half*)take((size_t)N * NCH * 2);
  __half* P1h  = (__half*)take((size_t)N * NCH * 2);
  __half* P2h  = (__half*)take((size_t)N * NCH * 2);
  __half* WFhi = (__half*)take((size_t)3 * 3 * 128 * 128 * 2);
  __half* WFlo = (__half*)take((size_t)3 * 3 * 128 * 128 * 2);
  float* sums  = (float*)take((size_t)NGRAPHS * NCH * 4);
  float* gcnt  = (float*)take((size_t)NGRAPHS * 4);

  hipMemsetAsync(sums, 0, (size_t)NGRAPHS * NCH * 4, stream);
  hipMemsetAsync(gcnt, 0, (size_t)NGRAPHS * 4, stream);

  prep_w_kernel<<<(3 * 3 * 128 * 128 + 255) / 256, 256, 0, stream>>>(W0, W1, W2, WFhi, WFlo);
  f2h_kernel<<<(N * NCH / 4 + 255) / 256, 256, 0, stream>>>(x, x16, N * NCH);

  part_count_kernel<<<NBLK, 256, 0, stream>>>(ei, pc, pcS, E, RB);
  offs_kernel<<<1, 256, 0, stream>>>(pc, pcS, pairOff, srcOff, gbase, sgbase, E);
  partition_kernel<<<NBLK, 256, 0, stream>>>(ei, pairOff, srcOff, dsts, srcs, srcpart, E, RB);
  {
    dim3 g(BXS, NR, 1);
    binD_kernel<<<g, 256, 0, stream>>>(dsts, gbase, pbinsD, RB);
    binS_kernel<<<g, 256, 0, stream>>>(srcpart, sgbase, pbinsS, RB);
  }
  sc_dis_kernel<<<(N + 255) / 256, 256, 0, stream>>>(pbinsS, dis, N, RB);
  range_scan_kernel<<<NR, 256, 0, stream>>>(pbinsD, sbase, RB);
  rp_kernel<<<(N + 1 + 255) / 256, 256, 0, stream>>>(sbase, gbase, rp, N, RB, E);
  {
    dim3 g(BXS, NR, 1);
    place_kernel<<<g, 256, 0, stream>>>(dsts, srcs, dis, sbase, gbase, sedge, RB);
  }

  int pgrid = (N + 3) / 4;
  int ggrid = (N + 127) / 128;
  const int WL = 3 * 4 * 8 * 512;  // halfs per layer in WF layout

  // layer 0
  prop_kernel<<<pgrid, 256, 0, stream>>>(x16, P1h, rp, sedge, N);
  prop_kernel<<<pgrid, 256, 0, stream>>>(P1h, P2h, rp, sedge, N);
  gemm_cheb_mfma<<<ggrid, 256, 0, stream>>>(x16, P1h, P2h, WFhi + 0 * WL, WFlo + 0 * WL, b0, H16, N, 1);
  // layer 1 (out aliases h; safe: blocks own disjoint rows, reads precede final barrier)
  prop_kernel<<<pgrid, 256, 0, stream>>>(H16, P1h, rp, sedge, N);
  prop_kernel<<<pgrid, 256, 0, stream>>>(P1h, P2h, rp, sedge, N);
  gemm_cheb_mfma<<<ggrid, 256, 0, stream>>>(H16, P1h, P2h, WFhi + 1 * WL, WFlo + 1 * WL, b1, H16, N, 1);
  // layer 2
  prop_kernel<<<pgrid, 256, 0, stream>>>(H16, P1h, rp, sedge, N);
  prop_kernel<<<pgrid, 256, 0, stream>>>(P1h, P2h, rp, sedge, N);
  gemm_cheb_mfma<<<ggrid, 256, 0, stream>>>(H16, P1h, P2h, WFhi + 2 * WL, WFlo + 2 * WL, b2, H16, N, 0);

  pool_kernel<<<(N + POOL_CHUNK - 1) / POOL_CHUNK, 128, 0, stream>>>(H16, batch, sums, gcnt, N);
  final_kernel<<<NGRAPHS, 16, 0, stream>>>(sums, gcnt, lw, lb, out);
}